// Round 15
// baseline (104.800 us; speedup 1.0000x reference)
//
#include <hip/hip_runtime.h>

#define C 128
#define HID 256
#define EPB 1024    // edges per block in bucket_scatter
#define BSH 8       // nodes per bucket = 256
#define CAP 12288   // tmp records per bucket (mean 4096, sigma 64 -> safe)
#define OUTCAP (CAP + 2048)   // padded src_w capacity per bucket

typedef __attribute__((ext_vector_type(8))) short bf16x8;
typedef __attribute__((ext_vector_type(4))) short s16x4;
typedef __attribute__((ext_vector_type(4))) float f32x4;

__device__ inline unsigned short f2b(float f) {
    unsigned u = __builtin_bit_cast(unsigned, f);
    unsigned r = u + 0x7fffu + ((u >> 16) & 1u);
    return (unsigned short)(r >> 16);
}

// ---------- fused: x -> bf16 copy | weight permute | zero bucket cursors ----------
// W-frag layout: lane l, elem j holds B[k][n]: n = nt*16+(l&15),
//                k = kk*32+16*(j>>2)+4*(l>>4)+(j&3)

__global__ __launch_bounds__(256) void fused_pre(
    const float* __restrict__ x, const float* __restrict__ W1,
    const float* __restrict__ W2, unsigned short* __restrict__ xb,
    unsigned short* __restrict__ W1p, unsigned short* __restrict__ W2p,
    int* __restrict__ cursor, long total4, int xblocks)
{
    const int bid = blockIdx.x;
    const int t = threadIdx.x;
    if (bid < xblocks) {
        long i = (long)bid * 256 + t;
        if (i < total4) {
            float4 v = *(const float4*)(x + i * 4);
            ushort4 o;
            o.x = f2b(v.x); o.y = f2b(v.y); o.z = f2b(v.z); o.w = f2b(v.w);
            *(ushort4*)(xb + i * 4) = o;
        }
    } else {
        if (bid == xblocks) cursor[t] = 0;   // 256 >= NB
        int tt = (bid - xblocks) * 256 + t;
        if (tt < C * HID) {
            {
                int j = tt & 7, l = (tt >> 3) & 63, kk = (tt >> 9) & 3, nt = tt >> 11;
                int n = nt * 16 + (l & 15);
                int k = kk * 32 + 16 * (j >> 2) + 4 * (l >> 4) + (j & 3);
                W1p[tt] = f2b(W1[k * HID + n]);
            }
            {
                int j = tt & 7, l = (tt >> 3) & 63, kk = (tt >> 9) & 7, nt = tt >> 12;
                int n = nt * 16 + (l & 15);
                int k = kk * 32 + 16 * (j >> 2) + 4 * (l >> 4) + (j & 3);
                W2p[tt] = f2b(W2[k * C + n]);
            }
        }
    }
}

// ---------- scatter: LDS-stage edges, histogram, atomic-reserve, write ----------

__global__ __launch_bounds__(256) void bucket_scatter(
    const int* __restrict__ ei, const float* __restrict__ ea,
    int* __restrict__ cursor, uint2* __restrict__ tmp, int E, int NB)
{
    __shared__ unsigned recx[EPB];        // 4 KB
    __shared__ float    recw[EPB];        // 4 KB
    __shared__ unsigned char bkt[EPB];    // 1 KB
    __shared__ int bins[256];             // counts -> running cursor
    const int t = threadIdx.x;
    const int base = blockIdx.x * EPB;
    const int n = min(EPB, E - base);
    bins[t] = 0;
    __syncthreads();
    for (int i = t; i < n; i += 256) {
        int src = ei[base + i];
        int dst = ei[E + base + i];
        recx[i] = (unsigned)src | ((unsigned)(dst & 255) << 24);   // src < 2^24
        recw[i] = ea[base + i];
        int b = dst >> BSH;
        bkt[i] = (unsigned char)b;
        atomicAdd(&bins[b], 1);
    }
    __syncthreads();
    int myCount = bins[t];
    __syncthreads();
    int myBase = 0;
    if (t < NB && myCount > 0) myBase = atomicAdd(&cursor[t], myCount);
    bins[t] = t * CAP + myBase;           // running global cursor for bucket t
    __syncthreads();
    for (int i = t; i < n; i += 256) {
        int b = bkt[i];
        int pos = atomicAdd(&bins[b], 1);
        tmp[pos] = uint2{recx[i], __builtin_bit_cast(unsigned, recw[i])};
    }
}

// ---------- counting sort within bucket -> padded src_w, deg, offs ----------

__global__ __launch_bounds__(256) void bucket_sort(
    const uint2* __restrict__ tmp, const int* __restrict__ cursor,
    uint2* __restrict__ src_w, int* __restrict__ deg_i, int* __restrict__ offs,
    int N)
{
    __shared__ int cnt[256];
    __shared__ int sc[256];
    const int b = blockIdx.x;
    const int t = threadIdx.x;
    const int s0 = b * CAP;
    const int s1 = s0 + cursor[b];
    const int pbase = b * OUTCAP;
    cnt[t] = 0;
    __syncthreads();
    for (int i = s0 + t; i < s1; i += 256)
        atomicAdd(&cnt[tmp[i].x >> 24], 1);
    __syncthreads();
    const int d = cnt[t];
    const int pd = (d + 7) & ~7;
    sc[t] = pd;
    __syncthreads();
    for (int off = 1; off < 256; off <<= 1) {
        int v = (t >= off) ? sc[t - off] : 0;
        __syncthreads();
        sc[t] += v;
        __syncthreads();
    }
    const int my_off = pbase + sc[t] - pd;   // exclusive padded position
    const int node = (b << BSH) + t;
    if (node < N) {
        deg_i[node] = d;
        offs[node]  = my_off;
    }
    cnt[t] = my_off;   // becomes cursor
    __syncthreads();
    for (int i = s0 + t; i < s1; i += 256) {
        uint2 r = tmp[i];
        int pos = atomicAdd(&cnt[r.x >> 24], 1);
        r.x &= 0x00ffffffu;
        src_w[pos] = r;
    }
    // fill pad slots with zero records (gathers hit hot row 0, weight 0)
    const uint2 zero{0u, 0u};
    for (int i = my_off + d; i < my_off + pd; ++i) src_w[i] = zero;
}

// ---------- fused aggregation + MLP: 64 nodes/block, 8 waves ----------
// Phase A: wave w aggregates nodes [w*8, w*8+8) into LDS o0S (bf16 pairs).
// Phase B: GEMM1 (wave owns 2 nt of 16), GEMM2 (wave owns 1 nt of 8).

__global__ __launch_bounds__(512, 6) void agg_mlp(
    const float* __restrict__ x, const unsigned short* __restrict__ xb,
    const int* __restrict__ offs, const int* __restrict__ deg_i,
    const uint2* __restrict__ src_w,
    const unsigned short* __restrict__ W1p, const float* __restrict__ b1,
    const unsigned short* __restrict__ W2p, const float* __restrict__ b2,
    float* __restrict__ out, int N)
{
    __shared__ unsigned o0S[64][66];        // 16.9 KB; row = 132 ushort (264 B)
    __shared__ unsigned short hS[64][264];  // 33.8 KB
    const int lane = threadIdx.x & 63;
    const int w    = threadIdx.x >> 6;      // 8 waves
    const int nodeBase = blockIdx.x * 64;

    // ---- Phase A: padded batch-16 gather-aggregate, 8 nodes per wave ----
    for (int k = 0; k < 8; ++k) {
        const int row  = w * 8 + k;
        const int node = nodeBase + row;
        unsigned pack = 0u;
        if (node < N) {
            const int rs = offs[node];
            const int d  = deg_i[node];
            const int pd = (d + 7) & ~7;
            const int c  = lane * 2;
            float a0 = 0.f, a1v = 0.f;
            int j = 0;
            for (; j + 16 <= pd; j += 16) {
                uint2 e[16];
                #pragma unroll
                for (int i = 0; i < 16; ++i) e[i] = src_w[rs + j + i];
                unsigned v[16];
                #pragma unroll
                for (int i = 0; i < 16; ++i)
                    v[i] = *(const unsigned*)(xb + (long)e[i].x * C + c);
                #pragma unroll
                for (int i = 0; i < 16; ++i) {
                    float wg = __builtin_bit_cast(float, e[i].y);
                    a0  = fmaf(__builtin_bit_cast(float, v[i] << 16), wg, a0);
                    a1v = fmaf(__builtin_bit_cast(float, v[i] & 0xffff0000u), wg, a1v);
                }
            }
            if (j < pd) {   // exactly one batch-8
                uint2 e[8];
                #pragma unroll
                for (int i = 0; i < 8; ++i) e[i] = src_w[rs + j + i];
                unsigned v[8];
                #pragma unroll
                for (int i = 0; i < 8; ++i)
                    v[i] = *(const unsigned*)(xb + (long)e[i].x * C + c);
                #pragma unroll
                for (int i = 0; i < 8; ++i) {
                    float wg = __builtin_bit_cast(float, e[i].y);
                    a0  = fmaf(__builtin_bit_cast(float, v[i] << 16), wg, a0);
                    a1v = fmaf(__builtin_bit_cast(float, v[i] & 0xffff0000u), wg, a1v);
                }
            }
            float inv = (d > 0) ? 1.f / (float)d : 1.f;
            float2 xv = *(const float2*)(x + (long)node * C + c);
            float o0 = 0.5f * (xv.x + a0 * inv);
            float o1 = 0.5f * (xv.y + a1v * inv);
            pack = (unsigned)f2b(o0) | ((unsigned)f2b(o1) << 16);
        }
        o0S[row][lane] = pack;
    }
    __syncthreads();

    const int r16 = lane & 15;
    const int grp = lane >> 4;

    // ---- GEMM1: wave w owns h cols [w*32, w*32+32) for all 64 rows ----
    bf16x8 bw1[2][4];
    #pragma unroll
    for (int n = 0; n < 2; ++n)
        #pragma unroll
        for (int kk = 0; kk < 4; ++kk)
            bw1[n][kk] = *(const bf16x8*)(W1p + ((((w * 2 + n) * 4 + kk) * 64 + lane) << 3));

    #pragma unroll
    for (int rt = 0; rt < 4; ++rt) {
        const unsigned short* ar = (const unsigned short*)o0S[rt * 16 + r16];
        bf16x8 a1[4];
        #pragma unroll
        for (int kk = 0; kk < 4; ++kk) {
            s16x4 lo = *(const s16x4*)(ar + kk * 32 + 4 * grp);
            s16x4 hi = *(const s16x4*)(ar + kk * 32 + 16 + 4 * grp);
            bf16x8 a;
            a[0] = lo[0]; a[1] = lo[1]; a[2] = lo[2]; a[3] = lo[3];
            a[4] = hi[0]; a[5] = hi[1]; a[6] = hi[2]; a[7] = hi[3];
            a1[kk] = a;
        }
        #pragma unroll
        for (int n = 0; n < 2; ++n) {
            f32x4 acc = {0.f, 0.f, 0.f, 0.f};
            #pragma unroll
            for (int kk = 0; kk < 4; ++kk)
                acc = __builtin_amdgcn_mfma_f32_16x16x32_bf16(a1[kk], bw1[n][kk], acc, 0, 0, 0);
            float bias = b1[(w * 2 + n) * 16 + r16];
            #pragma unroll
            for (int r = 0; r < 4; ++r) {
                float h = fmaxf(acc[r] + bias, 0.f);
                hS[rt * 16 + grp * 4 + r][(w * 2 + n) * 16 + r16] = f2b(h);
            }
        }
    }

    __syncthreads();

    // ---- GEMM2: wave w owns out cols [w*16, w*16+16) for all 64 rows ----
    bf16x8 bw2[8];
    #pragma unroll
    for (int kk = 0; kk < 8; ++kk)
        bw2[kk] = *(const bf16x8*)(W2p + (((w * 8 + kk) * 64 + lane) << 3));

    const float bias2 = b2[w * 16 + r16];
    #pragma unroll
    for (int rt = 0; rt < 4; ++rt) {
        bf16x8 a2[8];
        #pragma unroll
        for (int kk = 0; kk < 8; ++kk) {
            s16x4 lo = *(const s16x4*)&hS[rt * 16 + r16][kk * 32 + 4 * grp];
            s16x4 hi = *(const s16x4*)&hS[rt * 16 + r16][kk * 32 + 16 + 4 * grp];
            bf16x8 a;
            a[0] = lo[0]; a[1] = lo[1]; a[2] = lo[2]; a[3] = lo[3];
            a[4] = hi[0]; a[5] = hi[1]; a[6] = hi[2]; a[7] = hi[3];
            a2[kk] = a;
        }
        f32x4 acc = {0.f, 0.f, 0.f, 0.f};
        #pragma unroll
        for (int kk = 0; kk < 8; ++kk)
            acc = __builtin_amdgcn_mfma_f32_16x16x32_bf16(a2[kk], bw2[kk], acc, 0, 0, 0);
        #pragma unroll
        for (int r = 0; r < 4; ++r) {
            int node = nodeBase + rt * 16 + grp * 4 + r;
            if (node < N) out[(long)node * C + w * 16 + r16] = acc[r] + bias2;
        }
    }
}

extern "C" void kernel_launch(void* const* d_in, const int* in_sizes, int n_in,
                              void* d_out, int out_size, void* d_ws, size_t ws_size,
                              hipStream_t stream) {
    const float* x  = (const float*)d_in[0];
    const int*   ei = (const int*)d_in[1];
    const float* ea = (const float*)d_in[2];
    const float* W1 = (const float*)d_in[3];
    const float* b1 = (const float*)d_in[4];
    const float* W2 = (const float*)d_in[5];
    const float* b2 = (const float*)d_in[6];
    float* out = (float*)d_out;
    const int N = in_sizes[0] / C;
    const int E = in_sizes[2];

    const int NB   = (N + 255) >> BSH;           // buckets (<=256 for N<=65536)
    const int NBLK = (E + EPB - 1) / EPB;        // edge blocks

    // workspace layout (16B-aligned chunks)
    char* p = (char*)d_ws;
    auto alloc = [&](size_t bytes) { char* q = p; p += (bytes + 15) & ~(size_t)15; return q; };
    int* deg_i   = (int*)alloc((size_t)N * 4);
    int* offs    = (int*)alloc((size_t)N * 4);
    int* cursor  = (int*)alloc(256 * 4);
    uint2* src_w = (uint2*)alloc((size_t)NB * OUTCAP * 8);
    uint2* tmp   = (uint2*)alloc((size_t)NB * CAP * 8);
    unsigned short* W1p = (unsigned short*)alloc((size_t)C * HID * 2);
    unsigned short* W2p = (unsigned short*)alloc((size_t)HID * C * 2);
    unsigned short* xb  = (unsigned short*)alloc((size_t)N * C * 2);

    const long total4 = ((long)N * C) / 4;
    const int xblocks = (int)((total4 + 255) / 256);
    const int wblocks = (C * HID + 255) / 256;

    fused_pre<<<xblocks + wblocks, 256, 0, stream>>>(
        x, W1, W2, xb, W1p, W2p, cursor, total4, xblocks);
    bucket_scatter<<<NBLK, 256, 0, stream>>>(ei, ea, cursor, tmp, E, NB);
    bucket_sort<<<NB, 256, 0, stream>>>(tmp, cursor, src_w, deg_i, offs, N);
    agg_mlp<<<(N + 63) / 64, 512, 0, stream>>>(
        x, xb, offs, deg_i, src_w, W1p, b1, W2p, b2, out, N);
}

// Round 16
// 91.345 us; speedup vs baseline: 1.1473x; 1.1473x over previous
//
#include <hip/hip_runtime.h>

#define C 128
#define HID 256
#define EPB 2048    // edges per block in bucket_scatter
#define BSH 8       // nodes per bucket = 256
#define CAP 12288   // tmp records per bucket (mean 4096, sigma 64 -> safe)
#define OUTCAP (CAP + 2048)   // padded src_w capacity per bucket

typedef __attribute__((ext_vector_type(8))) short bf16x8;
typedef __attribute__((ext_vector_type(4))) short s16x4;
typedef __attribute__((ext_vector_type(4))) float f32x4;

__device__ inline unsigned short f2b(float f) {
    unsigned u = __builtin_bit_cast(unsigned, f);
    unsigned r = u + 0x7fffu + ((u >> 16) & 1u);
    return (unsigned short)(r >> 16);
}

// ---------- fused: x -> bf16 copy | weight permute | zero bucket cursors ----------
// W-frag layout: lane l, elem j holds B[k][n]: n = nt*16+(l&15),
//                k = kk*32+16*(j>>2)+4*(l>>4)+(j&3)

__global__ __launch_bounds__(256) void fused_pre(
    const float* __restrict__ x, const float* __restrict__ W1,
    const float* __restrict__ W2, unsigned short* __restrict__ xb,
    unsigned short* __restrict__ W1p, unsigned short* __restrict__ W2p,
    int* __restrict__ cursor, long total4, int xblocks)
{
    const int bid = blockIdx.x;
    const int t = threadIdx.x;
    if (bid < xblocks) {
        long i = (long)bid * 256 + t;
        if (i < total4) {
            float4 v = *(const float4*)(x + i * 4);
            ushort4 o;
            o.x = f2b(v.x); o.y = f2b(v.y); o.z = f2b(v.z); o.w = f2b(v.w);
            *(ushort4*)(xb + i * 4) = o;
        }
    } else {
        if (bid == xblocks) cursor[t] = 0;   // 256 >= NB
        int tt = (bid - xblocks) * 256 + t;
        if (tt < C * HID) {
            {
                int j = tt & 7, l = (tt >> 3) & 63, kk = (tt >> 9) & 3, nt = tt >> 11;
                int n = nt * 16 + (l & 15);
                int k = kk * 32 + 16 * (j >> 2) + 4 * (l >> 4) + (j & 3);
                W1p[tt] = f2b(W1[k * HID + n]);
            }
            {
                int j = tt & 7, l = (tt >> 3) & 63, kk = (tt >> 9) & 7, nt = tt >> 12;
                int n = nt * 16 + (l & 15);
                int k = kk * 32 + 16 * (j >> 2) + 4 * (l >> 4) + (j & 3);
                W2p[tt] = f2b(W2[k * C + n]);
            }
        }
    }
}

// ---------- scatter: LDS-stage edges, histogram, atomic-reserve, write ----------

__global__ __launch_bounds__(256) void bucket_scatter(
    const int* __restrict__ ei, const float* __restrict__ ea,
    int* __restrict__ cursor, uint2* __restrict__ tmp, int E, int NB)
{
    __shared__ unsigned recx[EPB];        // 8 KB
    __shared__ float    recw[EPB];        // 8 KB
    __shared__ unsigned char bkt[EPB];    // 2 KB
    __shared__ int bins[256];             // counts -> running cursor
    const int t = threadIdx.x;
    const int base = blockIdx.x * EPB;
    const int n = min(EPB, E - base);
    bins[t] = 0;
    __syncthreads();
    for (int i = t; i < n; i += 256) {
        int src = ei[base + i];
        int dst = ei[E + base + i];
        recx[i] = (unsigned)src | ((unsigned)(dst & 255) << 24);   // src < 2^24
        recw[i] = ea[base + i];
        int b = dst >> BSH;
        bkt[i] = (unsigned char)b;
        atomicAdd(&bins[b], 1);
    }
    __syncthreads();
    int myCount = bins[t];
    __syncthreads();
    int myBase = 0;
    if (t < NB && myCount > 0) myBase = atomicAdd(&cursor[t], myCount);
    bins[t] = t * CAP + myBase;           // running global cursor for bucket t
    __syncthreads();
    for (int i = t; i < n; i += 256) {
        int b = bkt[i];
        int pos = atomicAdd(&bins[b], 1);
        tmp[pos] = uint2{recx[i], __builtin_bit_cast(unsigned, recw[i])};
    }
}

// ---------- counting sort within bucket -> padded src_w, deg, offs ----------

__global__ __launch_bounds__(256) void bucket_sort(
    const uint2* __restrict__ tmp, const int* __restrict__ cursor,
    uint2* __restrict__ src_w, int* __restrict__ deg_i, int* __restrict__ offs,
    int N)
{
    __shared__ int cnt[256];
    __shared__ int sc[256];
    const int b = blockIdx.x;
    const int t = threadIdx.x;
    const int s0 = b * CAP;
    const int s1 = s0 + cursor[b];
    const int pbase = b * OUTCAP;
    cnt[t] = 0;
    __syncthreads();
    for (int i = s0 + t; i < s1; i += 256)
        atomicAdd(&cnt[tmp[i].x >> 24], 1);
    __syncthreads();
    const int d = cnt[t];
    const int pd = (d + 7) & ~7;
    sc[t] = pd;
    __syncthreads();
    for (int off = 1; off < 256; off <<= 1) {
        int v = (t >= off) ? sc[t - off] : 0;
        __syncthreads();
        sc[t] += v;
        __syncthreads();
    }
    const int my_off = pbase + sc[t] - pd;   // exclusive padded position
    const int node = (b << BSH) + t;
    if (node < N) {
        deg_i[node] = d;
        offs[node]  = my_off;
    }
    cnt[t] = my_off;   // becomes cursor
    __syncthreads();
    for (int i = s0 + t; i < s1; i += 256) {
        uint2 r = tmp[i];
        int pos = atomicAdd(&cnt[r.x >> 24], 1);
        r.x &= 0x00ffffffu;
        src_w[pos] = r;
    }
    // fill pad slots with zero records (gathers hit hot row 0, weight 0)
    const uint2 zero{0u, 0u};
    for (int i = my_off + d; i < my_off + pd; ++i) src_w[i] = zero;
}

// ---------- fused aggregation + MLP: 64 nodes/block, 8 waves ----------
// Single aliased LDS buffer buf[64][132] words (33.8 KB -> 4 blocks/CU):
//   Phase A writes o0 (words 0..63 of each row).
//   GEMM1 rt-iteration consumes o0 rows [16rt,16rt+16) then REWRITES the
//   same rows as h (264 bf16 = 132 words) after a barrier.
//   GEMM2 reads h rows.

__global__ __launch_bounds__(512, 8) void agg_mlp(
    const float* __restrict__ x, const unsigned short* __restrict__ xb,
    const int* __restrict__ offs, const int* __restrict__ deg_i,
    const uint2* __restrict__ src_w,
    const unsigned short* __restrict__ W1p, const float* __restrict__ b1,
    const unsigned short* __restrict__ W2p, const float* __restrict__ b2,
    float* __restrict__ out, int N)
{
    __shared__ unsigned buf[64][132];       // 33.8 KB, aliased o0/h
    const int lane = threadIdx.x & 63;
    const int w    = threadIdx.x >> 6;      // 8 waves
    const int nodeBase = blockIdx.x * 64;

    // ---- Phase A: padded batch-16 gather-aggregate, 8 nodes per wave ----
    for (int k = 0; k < 8; ++k) {
        const int row  = w * 8 + k;
        const int node = nodeBase + row;
        unsigned pack = 0u;
        if (node < N) {
            const int rs = offs[node];
            const int d  = deg_i[node];
            const int pd = (d + 7) & ~7;
            const int c  = lane * 2;
            float a0 = 0.f, a1v = 0.f;
            int j = 0;
            for (; j + 16 <= pd; j += 16) {
                uint2 e[16];
                #pragma unroll
                for (int i = 0; i < 16; ++i) e[i] = src_w[rs + j + i];
                unsigned v[16];
                #pragma unroll
                for (int i = 0; i < 16; ++i)
                    v[i] = *(const unsigned*)(xb + (long)e[i].x * C + c);
                #pragma unroll
                for (int i = 0; i < 16; ++i) {
                    float wg = __builtin_bit_cast(float, e[i].y);
                    a0  = fmaf(__builtin_bit_cast(float, v[i] << 16), wg, a0);
                    a1v = fmaf(__builtin_bit_cast(float, v[i] & 0xffff0000u), wg, a1v);
                }
            }
            if (j < pd) {   // exactly one batch-8
                uint2 e[8];
                #pragma unroll
                for (int i = 0; i < 8; ++i) e[i] = src_w[rs + j + i];
                unsigned v[8];
                #pragma unroll
                for (int i = 0; i < 8; ++i)
                    v[i] = *(const unsigned*)(xb + (long)e[i].x * C + c);
                #pragma unroll
                for (int i = 0; i < 8; ++i) {
                    float wg = __builtin_bit_cast(float, e[i].y);
                    a0  = fmaf(__builtin_bit_cast(float, v[i] << 16), wg, a0);
                    a1v = fmaf(__builtin_bit_cast(float, v[i] & 0xffff0000u), wg, a1v);
                }
            }
            float inv = (d > 0) ? 1.f / (float)d : 1.f;
            float2 xv = *(const float2*)(x + (long)node * C + c);
            float o0 = 0.5f * (xv.x + a0 * inv);
            float o1 = 0.5f * (xv.y + a1v * inv);
            pack = (unsigned)f2b(o0) | ((unsigned)f2b(o1) << 16);
        }
        buf[row][lane] = pack;
    }
    __syncthreads();

    const int r16 = lane & 15;
    const int grp = lane >> 4;

    // ---- GEMM1: wave w owns h cols [w*32, w*32+32) for all 64 rows ----
    bf16x8 bw1[2][4];
    #pragma unroll
    for (int n = 0; n < 2; ++n)
        #pragma unroll
        for (int kk = 0; kk < 4; ++kk)
            bw1[n][kk] = *(const bf16x8*)(W1p + ((((w * 2 + n) * 4 + kk) * 64 + lane) << 3));

    #pragma unroll
    for (int rt = 0; rt < 4; ++rt) {
        const unsigned short* ar = (const unsigned short*)&buf[rt * 16 + r16][0];
        bf16x8 a1[4];
        #pragma unroll
        for (int kk = 0; kk < 4; ++kk) {
            s16x4 lo = *(const s16x4*)(ar + kk * 32 + 4 * grp);
            s16x4 hi = *(const s16x4*)(ar + kk * 32 + 16 + 4 * grp);
            bf16x8 a;
            a[0] = lo[0]; a[1] = lo[1]; a[2] = lo[2]; a[3] = lo[3];
            a[4] = hi[0]; a[5] = hi[1]; a[6] = hi[2]; a[7] = hi[3];
            a1[kk] = a;
        }
        __syncthreads();   // all waves done reading o0 rows [16rt,16rt+16)
        #pragma unroll
        for (int n = 0; n < 2; ++n) {
            f32x4 acc = {0.f, 0.f, 0.f, 0.f};
            #pragma unroll
            for (int kk = 0; kk < 4; ++kk)
                acc = __builtin_amdgcn_mfma_f32_16x16x32_bf16(a1[kk], bw1[n][kk], acc, 0, 0, 0);
            float bias = b1[(w * 2 + n) * 16 + r16];
            #pragma unroll
            for (int r = 0; r < 4; ++r) {
                float h = fmaxf(acc[r] + bias, 0.f);
                ((unsigned short*)&buf[rt * 16 + grp * 4 + r][0])[(w * 2 + n) * 16 + r16] = f2b(h);
            }
        }
    }

    __syncthreads();   // all h rows written

    // ---- GEMM2: wave w owns out cols [w*16, w*16+16) for all 64 rows ----
    bf16x8 bw2[8];
    #pragma unroll
    for (int kk = 0; kk < 8; ++kk)
        bw2[kk] = *(const bf16x8*)(W2p + (((w * 8 + kk) * 64 + lane) << 3));

    const float bias2 = b2[w * 16 + r16];
    #pragma unroll
    for (int rt = 0; rt < 4; ++rt) {
        const unsigned short* hr = (const unsigned short*)&buf[rt * 16 + r16][0];
        bf16x8 a2[8];
        #pragma unroll
        for (int kk = 0; kk < 8; ++kk) {
            s16x4 lo = *(const s16x4*)(hr + kk * 32 + 4 * grp);
            s16x4 hi = *(const s16x4*)(hr + kk * 32 + 16 + 4 * grp);
            bf16x8 a;
            a[0] = lo[0]; a[1] = lo[1]; a[2] = lo[2]; a[3] = lo[3];
            a[4] = hi[0]; a[5] = hi[1]; a[6] = hi[2]; a[7] = hi[3];
            a2[kk] = a;
        }
        f32x4 acc = {0.f, 0.f, 0.f, 0.f};
        #pragma unroll
        for (int kk = 0; kk < 8; ++kk)
            acc = __builtin_amdgcn_mfma_f32_16x16x32_bf16(a2[kk], bw2[kk], acc, 0, 0, 0);
        #pragma unroll
        for (int r = 0; r < 4; ++r) {
            int node = nodeBase + rt * 16 + grp * 4 + r;
            if (node < N) out[(long)node * C + w * 16 + r16] = acc[r] + bias2;
        }
    }
}

extern "C" void kernel_launch(void* const* d_in, const int* in_sizes, int n_in,
                              void* d_out, int out_size, void* d_ws, size_t ws_size,
                              hipStream_t stream) {
    const float* x  = (const float*)d_in[0];
    const int*   ei = (const int*)d_in[1];
    const float* ea = (const float*)d_in[2];
    const float* W1 = (const float*)d_in[3];
    const float* b1 = (const float*)d_in[4];
    const float* W2 = (const float*)d_in[5];
    const float* b2 = (const float*)d_in[6];
    float* out = (float*)d_out;
    const int N = in_sizes[0] / C;
    const int E = in_sizes[2];

    const int NB   = (N + 255) >> BSH;           // buckets (<=256 for N<=65536)
    const int NBLK = (E + EPB - 1) / EPB;        // edge blocks

    // workspace layout (16B-aligned chunks)
    char* p = (char*)d_ws;
    auto alloc = [&](size_t bytes) { char* q = p; p += (bytes + 15) & ~(size_t)15; return q; };
    int* deg_i   = (int*)alloc((size_t)N * 4);
    int* offs    = (int*)alloc((size_t)N * 4);
    int* cursor  = (int*)alloc(256 * 4);
    uint2* src_w = (uint2*)alloc((size_t)NB * OUTCAP * 8);
    uint2* tmp   = (uint2*)alloc((size_t)NB * CAP * 8);
    unsigned short* W1p = (unsigned short*)alloc((size_t)C * HID * 2);
    unsigned short* W2p = (unsigned short*)alloc((size_t)HID * C * 2);
    unsigned short* xb  = (unsigned short*)alloc((size_t)N * C * 2);

    const long total4 = ((long)N * C) / 4;
    const int xblocks = (int)((total4 + 255) / 256);
    const int wblocks = (C * HID + 255) / 256;

    fused_pre<<<xblocks + wblocks, 256, 0, stream>>>(
        x, W1, W2, xb, W1p, W2p, cursor, total4, xblocks);
    bucket_scatter<<<NBLK, 256, 0, stream>>>(ei, ea, cursor, tmp, E, NB);
    bucket_sort<<<NB, 256, 0, stream>>>(tmp, cursor, src_w, deg_i, offs, N);
    agg_mlp<<<(N + 63) / 64, 512, 0, stream>>>(
        x, xb, offs, deg_i, src_w, W1p, b1, W2p, b2, out, N);
}